// Round 1
// baseline (784.617 us; speedup 1.0000x reference)
//
#include <hip/hip_runtime.h>
#include <hip/hip_bf16.h>
#include <hip/hip_fp16.h>

constexpr int INC  = 32;
constexpr int OUTC = 32;

typedef __bf16 bf16x8 __attribute__((ext_vector_type(8)));
typedef float  f32x4  __attribute__((ext_vector_type(4)));

// ---------------------------------------------------------------------------
// MFMA scatter conv, 64-bit fixed-point atomics.
//   R3 counters: 172.8M pk-f16 atomics @ 305 G/s = the wall (MfmaUtil 1.5%,
//   HBM 30%). This version packs FOUR channels per atomic as balanced signed
//   16-bit digits in one u64 (q0 + q1<<16 + q2<<32 + q3<<48, int64 math so
//   signed digits borrow coherently; atomic sum exact mod 2^64; decode peels
//   signed digits low->high). 8 atomics / contribution row instead of 16.
//   Scale 256 => step 3.9e-3, digit sums bounded ~27k << 32767.
// ---------------------------------------------------------------------------
__global__ __launch_bounds__(256) void scatter_conv_mfma_i64(
    const float* __restrict__ feats,    // [N][32]
    const float* __restrict__ wkern,    // [K][32][32]
    const int*   __restrict__ in_idx,   // [K][N]
    const int*   __restrict__ out_idx,  // [K][N]
    unsigned long long* __restrict__ ws, // [N][8] u64 digit accumulator (zeroed)
    int N)
{
    const int k    = blockIdx.y;
    const int lane = threadIdx.x & 63;
    const int col  = lane & 15;
    const int quad = lane >> 4;
    const int par  = col & 1;        // even/odd lane of the pair
    const int w    = col >> 1;       // u64 word index within the row (0..7)

    const int wave   = blockIdx.x * 4 + (threadIdx.x >> 6);
    const int nwaves = gridDim.x * 4;

    // B fragments, column-permuted: acc0 -> channel 2*col, acc1 -> 2*col+1
    const float* wk = wkern + (size_t)k * (INC * OUTC);
    bf16x8 b0, b1;
#pragma unroll
    for (int j = 0; j < 8; ++j) {
        const int kk = quad * 8 + j;
        b0[j] = (__bf16)wk[kk * OUTC + 2 * col];
        b1[j] = (__bf16)wk[kk * OUTC + 2 * col + 1];
    }

    const int* iin_p  = in_idx  + (size_t)k * N;
    const int* iout_p = out_idx + (size_t)k * N;
    const int  ntiles = N >> 4;

    for (int t = wave; t < ntiles; t += nwaves) {
        const int base = t << 4;

        const int iin = iin_p[base + col];            // A-row index for lane's m
        const int4 ov = *(const int4*)(iout_p + base + quad * 4);  // 16B aligned
        int orow[4] = {ov.x, ov.y, ov.z, ov.w};

        const float4* ap = (const float4*)(feats + (size_t)iin * INC + quad * 8);
        const float4 a_lo = ap[0];
        const float4 a_hi = ap[1];
        bf16x8 a;
        a[0] = (__bf16)a_lo.x; a[1] = (__bf16)a_lo.y;
        a[2] = (__bf16)a_lo.z; a[3] = (__bf16)a_lo.w;
        a[4] = (__bf16)a_hi.x; a[5] = (__bf16)a_hi.y;
        a[6] = (__bf16)a_hi.z; a[7] = (__bf16)a_hi.w;

        f32x4 acc0 = {0.f, 0.f, 0.f, 0.f};
        f32x4 acc1 = {0.f, 0.f, 0.f, 0.f};
        acc0 = __builtin_amdgcn_mfma_f32_16x16x32_bf16(a, b0, acc0, 0, 0, 0);
        acc1 = __builtin_amdgcn_mfma_f32_16x16x32_bf16(a, b1, acc1, 0, 0, 0);

        // Encode lane's 2 channels as one int32 (digits d0,d1), swap with the
        // paired lane (col^1, one DPP op), then the lane whose parity matches
        // r&1 issues the u64 atomic for (row=quad*4+r, word w).
#pragma unroll
        for (int r = 0; r < 4; ++r) {
            const float v0 = fminf(fmaxf(acc0[r], -64.f), 64.f);  // defensive
            const float v1 = fminf(fmaxf(acc1[r], -64.f), 64.f);
            const int q0 = __float2int_rn(v0 * 256.0f);
            const int q1 = __float2int_rn(v1 * 256.0f);
            const int sr = q0 + (int)((unsigned)q1 << 16);        // exact: |q|<=16384
            const int other = __shfl_xor(sr, 1);
            if ((r & 1) == par) {
                const int lo32 = par ? other : sr;   // channels 4w, 4w+1
                const int hi32 = par ? sr : other;   // channels 4w+2, 4w+3
                const unsigned long long C =
                    (unsigned long long)(long long)lo32 +
                    ((unsigned long long)(unsigned int)hi32 << 32);
                atomicAdd(ws + (size_t)orow[r] * 8 + w, C);
            }
        }
    }
}

// Decode + BN + ReLU: one u64 word (4 channels) per thread -> float4 store.
__global__ __launch_bounds__(256) void bn_relu_decode(
    const unsigned long long* __restrict__ ws,
    float* __restrict__ out,
    const float* __restrict__ gamma,
    const float* __restrict__ beta,
    const float* __restrict__ mean,
    const float* __restrict__ var,
    int nwords)   // N*8
{
    const int tid    = blockIdx.x * blockDim.x + threadIdx.x;
    const int stride = gridDim.x * blockDim.x;   // multiple of 8 (1024*256)
    const int wrd    = tid & 7;                  // word within row, invariant
    const int c0     = wrd * 4;

    float s[4], q[4];
#pragma unroll
    for (int j = 0; j < 4; ++j) {
        s[j] = gamma[c0 + j] * rsqrtf(var[c0 + j] + 1e-5f);
        q[j] = beta[c0 + j] - mean[c0 + j] * s[j];
    }

    float4* po = (float4*)out;
    for (int i = tid; i < nwords; i += stride) {
        long long t = (long long)ws[i];
        const int d0 = (int)(short)(t & 0xFFFF); t = (t - d0) >> 16;
        const int d1 = (int)(short)(t & 0xFFFF); t = (t - d1) >> 16;
        const int d2 = (int)(short)(t & 0xFFFF); t = (t - d2) >> 16;
        const int d3 = (int)t;
        float4 o4;
        o4.x = fmaxf(fmaf((float)d0 * (1.f / 256.f), s[0], q[0]), 0.f);
        o4.y = fmaxf(fmaf((float)d1 * (1.f / 256.f), s[1], q[1]), 0.f);
        o4.z = fmaxf(fmaf((float)d2 * (1.f / 256.f), s[2], q[2]), 0.f);
        o4.w = fmaxf(fmaf((float)d3 * (1.f / 256.f), s[3], q[3]), 0.f);
        po[i] = o4;
    }
}

// ------------------------- fp32 fallback (R2 path) -------------------------
__global__ __launch_bounds__(256) void scatter_conv_mfma_f32(
    const float* __restrict__ feats,
    const float* __restrict__ wkern,
    const int*   __restrict__ in_idx,
    const int*   __restrict__ out_idx,
    float*       __restrict__ out,
    int N)
{
    const int k    = blockIdx.y;
    const int lane = threadIdx.x & 63;
    const int col  = lane & 15;
    const int quad = lane >> 4;
    const int wave   = blockIdx.x * 4 + (threadIdx.x >> 6);
    const int nwaves = gridDim.x * 4;

    const float* wk = wkern + (size_t)k * (INC * OUTC);
    bf16x8 b0, b1;
#pragma unroll
    for (int j = 0; j < 8; ++j) {
        const int kk = quad * 8 + j;
        b0[j] = (__bf16)wk[kk * OUTC + col];
        b1[j] = (__bf16)wk[kk * OUTC + 16 + col];
    }

    const int* iin_p  = in_idx  + (size_t)k * N;
    const int* iout_p = out_idx + (size_t)k * N;
    const int  ntiles = N >> 4;

    for (int t = wave; t < ntiles; t += nwaves) {
        const int base = t << 4;
        const int iin = iin_p[base + col];
        int orow[4];
#pragma unroll
        for (int r = 0; r < 4; ++r) orow[r] = iout_p[base + quad * 4 + r];

        const float4* ap = (const float4*)(feats + (size_t)iin * INC + quad * 8);
        const float4 a_lo = ap[0];
        const float4 a_hi = ap[1];
        bf16x8 a;
        a[0] = (__bf16)a_lo.x; a[1] = (__bf16)a_lo.y;
        a[2] = (__bf16)a_lo.z; a[3] = (__bf16)a_lo.w;
        a[4] = (__bf16)a_hi.x; a[5] = (__bf16)a_hi.y;
        a[6] = (__bf16)a_hi.z; a[7] = (__bf16)a_hi.w;

        f32x4 acc0 = {0.f, 0.f, 0.f, 0.f};
        f32x4 acc1 = {0.f, 0.f, 0.f, 0.f};
        acc0 = __builtin_amdgcn_mfma_f32_16x16x32_bf16(a, b0, acc0, 0, 0, 0);
        acc1 = __builtin_amdgcn_mfma_f32_16x16x32_bf16(a, b1, acc1, 0, 0, 0);

#pragma unroll
        for (int r = 0; r < 4; ++r) {
            float* dst = out + (size_t)orow[r] * OUTC + col;
            unsafeAtomicAdd(dst,      acc0[r]);
            unsafeAtomicAdd(dst + 16, acc1[r]);
        }
    }
}

__global__ __launch_bounds__(256) void bn_relu_f32_inplace(
    float* __restrict__ out,
    const float* __restrict__ gamma,
    const float* __restrict__ beta,
    const float* __restrict__ mean,
    const float* __restrict__ var,
    int total4)
{
    const int tid    = blockIdx.x * blockDim.x + threadIdx.x;
    const int stride = gridDim.x * blockDim.x;
    const int c0     = (tid & 7) << 2;

    float s[4], b[4];
#pragma unroll
    for (int j = 0; j < 4; ++j) {
        const int c = c0 + j;
        s[j] = gamma[c] * rsqrtf(var[c] + 1e-5f);
        b[j] = beta[c] - mean[c] * s[j];
    }

    float4* p = (float4*)out;
    for (int i = tid; i < total4; i += stride) {
        float4 v = p[i];
        v.x = fmaxf(fmaf(v.x, s[0], b[0]), 0.0f);
        v.y = fmaxf(fmaf(v.y, s[1], b[1]), 0.0f);
        v.z = fmaxf(fmaf(v.z, s[2], b[2]), 0.0f);
        v.w = fmaxf(fmaf(v.w, s[3], b[3]), 0.0f);
        p[i] = v;
    }
}

extern "C" void kernel_launch(void* const* d_in, const int* in_sizes, int n_in,
                              void* d_out, int out_size, void* d_ws, size_t ws_size,
                              hipStream_t stream) {
    const float* feats   = (const float*)d_in[0];
    const float* wkern   = (const float*)d_in[1];
    const float* gamma   = (const float*)d_in[2];
    const float* beta    = (const float*)d_in[3];
    const float* mean    = (const float*)d_in[4];
    const float* var     = (const float*)d_in[5];
    const int*   in_idx  = (const int*)d_in[6];
    const int*   out_idx = (const int*)d_in[7];
    float*       out     = (float*)d_out;

    const int N = in_sizes[0] / INC;                  // 400000
    const int K = in_sizes[1] / (INC * OUTC);         // 27

    const size_t need = (size_t)N * 8 * sizeof(unsigned long long);  // 25.6 MB
    dim3 grid(80, K);

    if (ws_size >= need) {
        unsigned long long* acc = (unsigned long long*)d_ws;
        hipMemsetAsync(acc, 0, need, stream);
        scatter_conv_mfma_i64<<<grid, 256, 0, stream>>>(feats, wkern, in_idx, out_idx, acc, N);
        bn_relu_decode<<<1024, 256, 0, stream>>>(acc, out, gamma, beta, mean, var, N * 8);
    } else {
        hipMemsetAsync(out, 0, (size_t)out_size * sizeof(float), stream);
        scatter_conv_mfma_f32<<<grid, 256, 0, stream>>>(feats, wkern, in_idx, out_idx, out, N);
        bn_relu_f32_inplace<<<1024, 256, 0, stream>>>(out, gamma, beta, mean, var, out_size / 4);
    }
}